// Round 1
// baseline (3179.109 us; speedup 1.0000x reference)
//
#include <hip/hip_runtime.h>

typedef short bf16x8 __attribute__((ext_vector_type(8)));
typedef unsigned short u16x8 __attribute__((ext_vector_type(8)));
typedef float f32x4 __attribute__((ext_vector_type(4)));

#define MFMA16(a, b, c) __builtin_amdgcn_mfma_f32_16x16x32_bf16((a), (b), (c), 0, 0, 0)

#define SCALEF 0.17677669529663687f  // 32^-0.5

__device__ __forceinline__ unsigned short f2bf(float f) {
  union { float f; unsigned u; } v; v.f = f;
  unsigned r = v.u + 0x7fffu + ((v.u >> 16) & 1u);  // RNE
  return (unsigned short)(r >> 16);
}

// ---------- prep kernels ----------
// Wt[n][k] = bf16(W[k][n]);  W is (K x N) row-major
__global__ __launch_bounds__(256) void transpose_cvt_k(const float* __restrict__ W,
    unsigned short* __restrict__ Wt, int K, int N) {
  int i = blockIdx.x * 256 + threadIdx.x;
  if (i >= N * K) return;
  int n = i / K, k = i - n * K;
  Wt[i] = f2bf(W[(long)k * N + n]);
}

// rpb[h][q][k] = bias_table[(dh+7)*15 + (dw+7)][h]
__global__ __launch_bounds__(256) void build_rpb_k(const float* __restrict__ bt,
    float* __restrict__ rpb) {
  int i = blockIdx.x * 256 + threadIdx.x;
  if (i >= 16 * 64 * 64) return;
  int h = i >> 12, q = (i >> 6) & 63, k = i & 63;
  int dh = (q >> 3) - (k >> 3) + 7;
  int dw = (q & 7) - (k & 7) + 7;
  rpb[i] = bt[(dh * 15 + dw) * 16 + h];
}

// ---------- GEMM: C[M,N] = A[M,K] @ Bt[N,K]^T + bias ----------
// AT = float (converted to bf16 while staging) or unsigned short (bf16 bits)
// OT = unsigned short (bf16) or float
template <typename AT, typename OT>
__global__ __launch_bounds__(256) void gemm_k(const AT* __restrict__ A,
    const unsigned short* __restrict__ Bt, const float* __restrict__ bias,
    OT* __restrict__ C, int M, int N, int K)
{
  constexpr bool A_F32 = (sizeof(AT) == 4);
  constexpr bool O_F32 = (sizeof(OT) == 4);

  const int tn = N >> 7;
  const int bm = blockIdx.x / tn;
  const int bn = blockIdx.x - bm * tn;
  const int tid = threadIdx.x;
  const int wave = tid >> 6, lane = tid & 63;
  const int wr = wave >> 1, wc = wave & 1;
  const int lg = lane >> 4, lc = lane & 15;

  __shared__ unsigned short Asm[128][72];  // +8 pad: 144B pitch, 2-way banks (free)
  __shared__ unsigned short Bsm[128][72];

  f32x4 acc[4][4];
#pragma unroll
  for (int i = 0; i < 4; ++i)
#pragma unroll
    for (int j = 0; j < 4; ++j)
      acc[i][j] = f32x4{0.f, 0.f, 0.f, 0.f};

  float4 aregf[8];
  uint4 aregh[4];
  uint4 breg[4];

  const long rowBase = (long)bm * 128;
  const int colBase = bn * 128;
  const int KT = K >> 6;

  auto loadA = [&](int kt) {
    if constexpr (A_F32) {
#pragma unroll
      for (int j = 0; j < 8; ++j) {
        int f = j * 256 + tid;
        int r = f >> 4, c4 = f & 15;               // 16 float4 per 64-wide row
        aregf[j] = *(const float4*)(A + (rowBase + r) * (long)K + kt * 64 + c4 * 4);
      }
    } else {
#pragma unroll
      for (int j = 0; j < 4; ++j) {
        int f = j * 256 + tid;
        int r = f >> 3, c8 = f & 7;                // 8 x (8 bf16) per row
        aregh[j] = *(const uint4*)(A + (rowBase + r) * (long)K + kt * 64 + c8 * 8);
      }
    }
  };
  auto loadB = [&](int kt) {
#pragma unroll
    for (int j = 0; j < 4; ++j) {
      int f = j * 256 + tid;
      int r = f >> 3, c8 = f & 7;
      breg[j] = *(const uint4*)(Bt + (long)(colBase + r) * K + kt * 64 + c8 * 8);
    }
  };
  auto storeLDS = [&]() {
    if constexpr (A_F32) {
#pragma unroll
      for (int j = 0; j < 8; ++j) {
        int f = j * 256 + tid;
        int r = f >> 4, c4 = f & 15;
        uint2 p;
        p.x = (unsigned)f2bf(aregf[j].x) | ((unsigned)f2bf(aregf[j].y) << 16);
        p.y = (unsigned)f2bf(aregf[j].z) | ((unsigned)f2bf(aregf[j].w) << 16);
        *(uint2*)&Asm[r][c4 * 4] = p;
      }
    } else {
#pragma unroll
      for (int j = 0; j < 4; ++j) {
        int f = j * 256 + tid;
        int r = f >> 3, c8 = f & 7;
        *(uint4*)&Asm[r][c8 * 8] = aregh[j];
      }
    }
#pragma unroll
    for (int j = 0; j < 4; ++j) {
      int f = j * 256 + tid;
      int r = f >> 3, c8 = f & 7;
      *(uint4*)&Bsm[r][c8 * 8] = breg[j];
    }
  };

  loadA(0); loadB(0);
  storeLDS();
  __syncthreads();

  for (int kt = 0; kt < KT; ++kt) {
    const bool more = (kt + 1 < KT);
    if (more) { loadA(kt + 1); loadB(kt + 1); }  // issue early; consumed after barrier
#pragma unroll
    for (int ks = 0; ks < 2; ++ks) {
      bf16x8 af[4], bfr[4];
#pragma unroll
      for (int mt = 0; mt < 4; ++mt)
        af[mt] = *(const bf16x8*)&Asm[wr * 64 + mt * 16 + lc][ks * 32 + lg * 8];
#pragma unroll
      for (int nt = 0; nt < 4; ++nt)
        bfr[nt] = *(const bf16x8*)&Bsm[wc * 64 + nt * 16 + lc][ks * 32 + lg * 8];
#pragma unroll
      for (int mt = 0; mt < 4; ++mt)
#pragma unroll
        for (int nt = 0; nt < 4; ++nt)
          acc[mt][nt] = MFMA16(af[mt], bfr[nt], acc[mt][nt]);
    }
    __syncthreads();
    if (more) { storeLDS(); __syncthreads(); }
  }

  // epilogue: bias + store
  float bv[4];
#pragma unroll
  for (int nt = 0; nt < 4; ++nt)
    bv[nt] = bias[colBase + wc * 64 + nt * 16 + lc];
#pragma unroll
  for (int mt = 0; mt < 4; ++mt)
#pragma unroll
    for (int nt = 0; nt < 4; ++nt)
#pragma unroll
      for (int r = 0; r < 4; ++r) {
        long row = rowBase + wr * 64 + mt * 16 + lg * 4 + r;
        int col = colBase + wc * 64 + nt * 16 + lc;
        float v = acc[mt][nt][r] + bv[nt];
        if constexpr (O_F32) C[row * N + col] = v;
        else                 C[row * N + col] = f2bf(v);
      }
}

// ---------- fused window attention ----------
// grid = 4096 windows, 256 threads = 4 waves; wave w handles heads 4w..4w+3
__global__ __launch_bounds__(256) void attn_k(
    const unsigned short* __restrict__ qh,   // [B*64][512] bf16
    const unsigned short* __restrict__ kvh,  // [B*64][1024] bf16 (k | v)
    const float* __restrict__ mask,          // [64][64][64]
    const float* __restrict__ rpb,           // [16][64][64]
    unsigned short* __restrict__ x)          // [B*64][512] bf16
{
  __shared__ unsigned short P[4][64][72];    // per-wave unnormalized probs
  __shared__ unsigned short Vt[4][32][72];   // per-wave V^T [d][token]

  const int b = blockIdx.x;
  const int w = b & 63;
  const int tid = threadIdx.x;
  const int wave = tid >> 6, lane = tid & 63;
  const int lg = lane >> 4, lc = lane & 15;
  const long rowQ = (long)b * 64;

  for (int hi = 0; hi < 4; ++hi) {
    const int h = wave * 4 + hi;

    // Q as A-frags, K as B-frags (d is K-dim = 32, one MFMA step)
    bf16x8 qf[4], kf[4];
#pragma unroll
    for (int mt = 0; mt < 4; ++mt)
      qf[mt] = *(const bf16x8*)(qh + (rowQ + mt * 16 + lc) * 512 + h * 32 + lg * 8);
#pragma unroll
    for (int nt = 0; nt < 4; ++nt)
      kf[nt] = *(const bf16x8*)(kvh + (rowQ + nt * 16 + lc) * 1024 + h * 32 + lg * 8);

    f32x4 acc[4][4];
#pragma unroll
    for (int mt = 0; mt < 4; ++mt)
#pragma unroll
      for (int nt = 0; nt < 4; ++nt)
        acc[mt][nt] = f32x4{0.f, 0.f, 0.f, 0.f};
#pragma unroll
    for (int mt = 0; mt < 4; ++mt)
#pragma unroll
      for (int nt = 0; nt < 4; ++nt)
        acc[mt][nt] = MFMA16(qf[mt], kf[nt], acc[mt][nt]);

    // stage V^T: lane = token, read 32 d's, scatter to Vt[d][token]
    {
      const unsigned short* vp = kvh + (rowQ + lane) * 1024 + 512 + h * 32;
      u16x8 v0 = *(const u16x8*)(vp);
      u16x8 v1 = *(const u16x8*)(vp + 8);
      u16x8 v2 = *(const u16x8*)(vp + 16);
      u16x8 v3 = *(const u16x8*)(vp + 24);
#pragma unroll
      for (int j = 0; j < 8; ++j) {
        Vt[wave][j][lane]      = v0[j];
        Vt[wave][8 + j][lane]  = v1[j];
        Vt[wave][16 + j][lane] = v2[j];
        Vt[wave][24 + j][lane] = v3[j];
      }
    }

    // scale + rpb + mask, row softmax (rows live in 16-lane groups)
    float pden[4][4];
#pragma unroll
    for (int mt = 0; mt < 4; ++mt) {
#pragma unroll
      for (int r = 0; r < 4; ++r) {
        const int qrow = mt * 16 + lg * 4 + r;
        const float* rp = rpb + h * 4096 + qrow * 64 + lc;
        const float* mp = mask + w * 4096 + qrow * 64 + lc;
        float sc[4];
#pragma unroll
        for (int nt = 0; nt < 4; ++nt)
          sc[nt] = acc[mt][nt][r] * SCALEF + rp[nt * 16] + mp[nt * 16];
        float mx = fmaxf(fmaxf(sc[0], sc[1]), fmaxf(sc[2], sc[3]));
        mx = fmaxf(mx, __shfl_xor(mx, 1));
        mx = fmaxf(mx, __shfl_xor(mx, 2));
        mx = fmaxf(mx, __shfl_xor(mx, 4));
        mx = fmaxf(mx, __shfl_xor(mx, 8));
        float s = 0.f;
#pragma unroll
        for (int nt = 0; nt < 4; ++nt) { sc[nt] = __expf(sc[nt] - mx); s += sc[nt]; }
        s += __shfl_xor(s, 1);
        s += __shfl_xor(s, 2);
        s += __shfl_xor(s, 4);
        s += __shfl_xor(s, 8);
        pden[mt][r] = 1.f / s;
#pragma unroll
        for (int nt = 0; nt < 4; ++nt)
          P[wave][qrow][nt * 16 + lc] = f2bf(sc[nt]);
      }
    }
    __syncthreads();

    // PV: x[q][d] = sum_tok P[q][tok] * V[tok][d]
    f32x4 xacc[4][2];
#pragma unroll
    for (int mt = 0; mt < 4; ++mt)
#pragma unroll
      for (int nt = 0; nt < 2; ++nt)
        xacc[mt][nt] = f32x4{0.f, 0.f, 0.f, 0.f};
#pragma unroll
    for (int ks = 0; ks < 2; ++ks) {
      bf16x8 pa[4], vb[2];
#pragma unroll
      for (int mt = 0; mt < 4; ++mt)
        pa[mt] = *(const bf16x8*)&P[wave][mt * 16 + lc][ks * 32 + lg * 8];
#pragma unroll
      for (int nt = 0; nt < 2; ++nt)
        vb[nt] = *(const bf16x8*)&Vt[wave][nt * 16 + lc][ks * 32 + lg * 8];
#pragma unroll
      for (int mt = 0; mt < 4; ++mt)
#pragma unroll
        for (int nt = 0; nt < 2; ++nt)
          xacc[mt][nt] = MFMA16(pa[mt], vb[nt], xacc[mt][nt]);
    }

    // normalize + store
#pragma unroll
    for (int mt = 0; mt < 4; ++mt)
#pragma unroll
      for (int nt = 0; nt < 2; ++nt)
#pragma unroll
        for (int r = 0; r < 4; ++r) {
          const int qrow = mt * 16 + lg * 4 + r;
          x[(rowQ + qrow) * 512 + h * 32 + nt * 16 + lc] =
              f2bf(xacc[mt][nt][r] * pden[mt][r]);
        }
    __syncthreads();
  }
}

extern "C" void kernel_launch(void* const* d_in, const int* in_sizes, int n_in,
                              void* d_out, int out_size, void* d_ws, size_t ws_size,
                              hipStream_t stream) {
  const float* q    = (const float*)d_in[0];
  const float* kv   = (const float*)d_in[1];
  const float* mask = (const float*)d_in[2];
  const float* Wq   = (const float*)d_in[3];
  const float* bq   = (const float*)d_in[4];
  const float* Wkv  = (const float*)d_in[5];
  const float* bkv  = (const float*)d_in[6];
  const float* btab = (const float*)d_in[7];
  const float* Wp   = (const float*)d_in[8];
  const float* bp   = (const float*)d_in[9];
  float* out = (float*)d_out;

  const int M = 4096 * 64;  // 262144 rows

  char* ws = (char*)d_ws;
  const size_t OFF_QH  = 0;                          // 256 MB
  const size_t OFF_KVH = OFF_QH + (size_t)M * 512 * 2;     // 512 MB
  const size_t OFF_X   = OFF_KVH + (size_t)M * 1024 * 2;   // 256 MB
  const size_t OFF_WQT = OFF_X + (size_t)M * 512 * 2;
  const size_t OFF_WKVT = OFF_WQT + 512 * 512 * 2;
  const size_t OFF_WPT  = OFF_WKVT + 1024 * 512 * 2;
  const size_t OFF_RPB  = OFF_WPT + 512 * 512 * 2;

  unsigned short* qh    = (unsigned short*)(ws + OFF_QH);
  unsigned short* kvh   = (unsigned short*)(ws + OFF_KVH);
  unsigned short* xb    = (unsigned short*)(ws + OFF_X);
  unsigned short* Wq_t  = (unsigned short*)(ws + OFF_WQT);
  unsigned short* Wkv_t = (unsigned short*)(ws + OFF_WKVT);
  unsigned short* Wp_t  = (unsigned short*)(ws + OFF_WPT);
  float* rpbf           = (float*)(ws + OFF_RPB);

  transpose_cvt_k<<<(512 * 512 + 255) / 256, 256, 0, stream>>>(Wq, Wq_t, 512, 512);
  transpose_cvt_k<<<(512 * 1024 + 255) / 256, 256, 0, stream>>>(Wkv, Wkv_t, 512, 1024);
  transpose_cvt_k<<<(512 * 512 + 255) / 256, 256, 0, stream>>>(Wp, Wp_t, 512, 512);
  build_rpb_k<<<(16 * 64 * 64 + 255) / 256, 256, 0, stream>>>(btab, rpbf);

  gemm_k<float, unsigned short><<<(M / 128) * (512 / 128), 256, 0, stream>>>(
      q, Wq_t, bq, qh, M, 512, 512);
  gemm_k<float, unsigned short><<<(M / 128) * (1024 / 128), 256, 0, stream>>>(
      kv, Wkv_t, bkv, kvh, M, 1024, 512);

  attn_k<<<4096, 256, 0, stream>>>(qh, kvh, mask, rpbf, xb);

  gemm_k<unsigned short, float><<<(M / 128) * (512 / 128), 256, 0, stream>>>(
      xb, Wp_t, bp, out, M, 512, 512);

  (void)in_sizes; (void)n_in; (void)out_size; (void)ws_size;
}